// Round 4
// baseline (828.893 us; speedup 1.0000x reference)
//
#include <hip/hip_runtime.h>
#include <hip/hip_bf16.h>

#define HW 65536
constexpr int IMG_W = 256;

typedef __attribute__((ext_vector_type(8))) short short8;
typedef __attribute__((ext_vector_type(4))) float f32x4;

__device__ __forceinline__ float bf2f(unsigned short u) {
    return __uint_as_float(((unsigned)u) << 16);
}
__device__ __forceinline__ unsigned short f2bf(float f) {
    __hip_bfloat16 h = __float2bfloat16(f);
    return *reinterpret_cast<unsigned short*>(&h);
}

// ================= stage 1: direct 3x3 conv, NCHW f32 in -> NHWC bf16 raw out =================
__global__ __launch_bounds__(256) void conv1_direct(
    const float* __restrict__ x, const float* __restrict__ wt,
    const float* __restrict__ bias, unsigned short* __restrict__ outraw)
{
    constexpr int CIN = 3, COUT = 32, OCB = 16;
    const int tile = blockIdx.x;
    const int ty0 = (tile >> 3) << 5;
    const int tx0 = (tile & 7) << 5;
    const int oc0 = blockIdx.y * OCB;
    const int b = blockIdx.z;

    __shared__ alignas(16) float s_in[CIN][34][36];
    __shared__ alignas(16) float s_w[CIN][9][OCB];

    const int tid = threadIdx.x;
    const int lx = tid & 31;
    const int ly = tid >> 5;

    float acc[4][OCB];
    #pragma unroll
    for (int j = 0; j < 4; ++j)
        #pragma unroll
        for (int oc = 0; oc < OCB; ++oc) acc[j][oc] = 0.f;

    for (int idx = tid; idx < CIN * 34 * 34; idx += 256) {
        int ic  = idx / (34 * 34);
        int rem = idx - ic * (34 * 34);
        int r   = rem / 34;
        int cc  = rem - r * 34;
        int gy = ty0 - 1 + r, gx = tx0 - 1 + cc;
        float v = 0.f;
        if ((unsigned)gy < 256u && (unsigned)gx < 256u)
            v = x[((size_t)(b * CIN + ic)) * HW + (size_t)gy * IMG_W + gx];
        s_in[ic][r][cc] = v;
    }
    for (int idx = tid; idx < CIN * 9 * OCB; idx += 256) {
        int oc  = idx & (OCB - 1);
        int t2  = idx >> 4;
        int tap = t2 % 9;
        int ic  = t2 / 9;
        s_w[ic][tap][oc] = wt[((size_t)(oc0 + oc) * CIN + ic) * 9 + tap];
    }
    __syncthreads();

    for (int ic = 0; ic < CIN; ++ic) {
        #pragma unroll
        for (int tap = 0; tap < 9; ++tap) {
            const int dy = tap / 3, dx = tap % 3;
            float wr[OCB];
            #pragma unroll
            for (int q = 0; q < OCB / 4; ++q)
                *(float4*)&wr[q * 4] = *(const float4*)&s_w[ic][tap][q * 4];
            #pragma unroll
            for (int j = 0; j < 4; ++j) {
                float iv = s_in[ic][ly + 8 * j + dy][lx + dx];
                #pragma unroll
                for (int oc = 0; oc < OCB; ++oc) acc[j][oc] += iv * wr[oc];
            }
        }
    }

    #pragma unroll
    for (int j = 0; j < 4; ++j) {
        const size_t p = ((size_t)b << 16) + (size_t)((ty0 + ly + 8 * j) << 8) + tx0 + lx;
        short8 v0, v1;
        #pragma unroll
        for (int k = 0; k < 8; ++k) {
            v0[k] = (short)f2bf(acc[j][k] + bias[oc0 + k]);
            v1[k] = (short)f2bf(acc[j][8 + k] + bias[oc0 + 8 + k]);
        }
        *(short8*)&outraw[p * COUT + oc0]     = v0;
        *(short8*)&outraw[p * COUT + oc0 + 8] = v1;
    }
}

// ================= weight repack: [oc][ic][3][3] f32 -> [k/8][oc][8] bf16 (k = tap*CIN+ic) ====
__global__ void repack2(const float* __restrict__ w, unsigned short* __restrict__ wp,
                        int COUT, int CIN)
{
    int i = blockIdx.x * 256 + threadIdx.x;
    int K9 = 9 * CIN;
    if (i >= COUT * K9) return;
    int oc = i / K9, k = i - oc * K9;
    int tap = k / CIN, ic = k - tap * CIN;
    wp[(size_t)(k >> 3) * COUT * 8 + oc * 8 + (k & 7)] =
        f2bf(w[((size_t)(oc * CIN + ic)) * 9 + tap]);
}

// ================= MFMA implicit-GEMM 3x3 conv (swapped operands) =================
// A-operand = weights (m=oc), B-operand = pixels (n=px) -> D reg dim = 4 consecutive oc.
// Wave = 64px (4 rows x 16 cols) x WOC oc. Block = WM x WN waves = (WM*4*16)px x (WN*WOC)oc.
// Block covers full COUT (no input re-staging). Fused prev-BN+leaky staging, fused stats.
template<int CIN, int COUT, int WM, int WN, int WOC>
__global__ __launch_bounds__(256, 2) void conv_mfma3(
    const unsigned short* __restrict__ in, const float2* __restrict__ coef,
    const unsigned short* __restrict__ wp, const float* __restrict__ bias,
    unsigned short* __restrict__ outraw, float2* __restrict__ partial)
{
    static_assert(WN * WOC == COUT, "block must cover full COUT");
    constexpr int CINP = CIN + 8;
    constexpr int ROWS = WM * 4;
    constexpr int NOCT = CIN / 8;
    constexpr int NG = WOC / 16;
    constexpr int ICB = CIN / 32;
    constexpr int TILES = (256 / ROWS) * 16;
    constexpr int NCHUNK = TILES * 8;

    __shared__ alignas(16) short s_in[(ROWS + 2) * 18 * CINP];
    __shared__ float2 s_coef[CIN];
    __shared__ float2 s_stat[4][128];

    const int tile = blockIdx.x;
    const int b = blockIdx.z;
    const int ty0 = (tile >> 4) * ROWS;
    const int tx0 = (tile & 15) * 16;
    const int tid = threadIdx.x;

    if (tid < CIN) s_coef[tid] = coef[tid];
    __syncthreads();

    // ---- stage input tile (halo, channels-last) with fused BN+leaky ----
    const size_t bbase = (size_t)b << 16;
    for (int idx = tid; idx < (ROWS + 2) * 18 * NOCT; idx += 256) {
        int ic8 = idx % NOCT;
        int rc  = idx / NOCT;
        int c = rc % 18, r = rc / 18;
        int gy = ty0 - 1 + r, gx = tx0 - 1 + c;
        short8 v = (short8)0;
        if ((unsigned)gy < 256u && (unsigned)gx < 256u) {
            short8 rawv = *(const short8*)&in[(bbase + (size_t)(gy << 8) + gx) * CIN + ic8 * 8];
            #pragma unroll
            for (int j = 0; j < 8; ++j) {
                float2 ab = s_coef[ic8 * 8 + j];
                float xv = fmaf(ab.x, bf2f((unsigned short)rawv[j]), ab.y);
                xv = fmaxf(xv, 0.01f * xv);
                v[j] = (short)f2bf(xv);
            }
        }
        *(short8*)&s_in[(r * 18 + c) * CINP + ic8 * 8] = v;
    }
    __syncthreads();

    const int lane = tid & 63;
    const int wv = tid >> 6;
    const int wm = wv / WN, wn = wv % WN;
    const int ln = lane & 15;
    const int grp = lane >> 4;

    f32x4 acc[4][NG] = {};

    // weight A-frag: oc = wn*WOC + g*16 + ln (m = lane&15), k-chunk = kc + grp
    const unsigned short* wpb = wp + ((size_t)grp * COUT + wn * WOC + ln) * 8;

    for (int tap = 0; tap < 9; ++tap) {
        const int dy = tap / 3, dx = tap - dy * 3;
        const int arow = (wm * 4 + dy) * 18 + ln + dx;
        const int kc0 = tap * (CIN / 8);
        #pragma unroll
        for (int icb = 0; icb < ICB; ++icb) {
            short8 wfr[NG];
            #pragma unroll
            for (int g = 0; g < NG; ++g)
                wfr[g] = *(const short8*)&wpb[((size_t)(kc0 + icb * 4) * COUT + g * 16) * 8];
            #pragma unroll
            for (int f = 0; f < 4; ++f) {
                short8 px = *(const short8*)&s_in[(arow + f * 18) * CINP + icb * 32 + grp * 8];
                #pragma unroll
                for (int g = 0; g < NG; ++g)
                    acc[f][g] = __builtin_amdgcn_mfma_f32_16x16x32_bf16(wfr[g], px, acc[f][g], 0, 0, 0);
            }
        }
    }

    // ---- epilogue: oc-contiguous 8B NHWC stores + in-register stats ----
    #pragma unroll
    for (int g = 0; g < NG; ++g) {
        const int ocl = wn * WOC + g * 16 + grp * 4;   // block-local oc == global oc (NOC=1)
        const f32x4 bias4 = *(const f32x4*)&bias[ocl];
        f32x4 vs = {}, vq = {};
        #pragma unroll
        for (int f = 0; f < 4; ++f) {
            const int row = ty0 + wm * 4 + f;
            f32x4 v = acc[f][g] + bias4;
            vs += v; vq += v * v;
            short4 sv;
            sv.x = (short)f2bf(v[0]); sv.y = (short)f2bf(v[1]);
            sv.z = (short)f2bf(v[2]); sv.w = (short)f2bf(v[3]);
            *(short4*)&outraw[(bbase + (size_t)(row << 8) + tx0 + ln) * COUT + ocl] = sv;
        }
        // reduce over the 16 px lanes
        #pragma unroll
        for (int d = 1; d < 16; d <<= 1) {
            #pragma unroll
            for (int r = 0; r < 4; ++r) {
                vs[r] += __shfl_xor(vs[r], d);
                vq[r] += __shfl_xor(vq[r], d);
            }
        }
        if (ln == 0) {
            #pragma unroll
            for (int r = 0; r < 4; ++r)
                s_stat[wv][g * 16 + grp * 4 + r] = make_float2(vs[r], vq[r]);
        }
    }
    __syncthreads();
    if (tid < COUT) {
        const int wn_o = tid / WOC, ol = tid - wn_o * WOC;
        float sx = 0.f, sq = 0.f;
        #pragma unroll
        for (int m = 0; m < WM; ++m) {
            float2 p = s_stat[m * WN + wn_o][ol];
            sx += p.x; sq += p.y;
        }
        partial[(size_t)tid * NCHUNK + b * TILES + tile] = make_float2(sx, sq);
    }
}

// ================= stage-1 BN stats over NHWC bf16 raw =================
template<int C>
__global__ __launch_bounds__(256) void bn_stats_nhwc(const unsigned short* __restrict__ raw,
                                                     float2* __restrict__ partial)
{
    constexpr int CPT = C / 8;
    constexpr int PPI = 256 / CPT;
    const int t = threadIdx.x;
    const int co = t % CPT, pg = t / CPT;
    const int p0 = blockIdx.x * 2048;
    float s[8], ss[8];
    #pragma unroll
    for (int j = 0; j < 8; ++j) { s[j] = 0.f; ss[j] = 0.f; }
    for (int p = p0 + pg; p < p0 + 2048; p += PPI) {
        short8 v = *(const short8*)&raw[(size_t)p * C + co * 8];
        #pragma unroll
        for (int j = 0; j < 8; ++j) {
            float xv = bf2f((unsigned short)v[j]);
            s[j] += xv; ss[j] += xv * xv;
        }
    }
    __shared__ float rs[256][8], rss[256][8];
    #pragma unroll
    for (int j = 0; j < 8; ++j) { rs[t][j] = s[j]; rss[t][j] = ss[j]; }
    __syncthreads();
    for (int off = PPI / 2; off > 0; off >>= 1) {
        if (pg < off) {
            #pragma unroll
            for (int j = 0; j < 8; ++j) {
                rs[t][j]  += rs[t + off * CPT][j];
                rss[t][j] += rss[t + off * CPT][j];
            }
        }
        __syncthreads();
    }
    if (pg == 0) {
        #pragma unroll
        for (int j = 0; j < 8; ++j)
            partial[(size_t)(co * 8 + j) * 256 + blockIdx.x] = make_float2(rs[t][j], rss[t][j]);
    }
}

// ================= finalize (stage 1 layout: [c][256]) =================
__global__ void bn_finalize_kernel(const float2* __restrict__ partial,
                                   const float* __restrict__ gamma,
                                   const float* __restrict__ beta,
                                   float2* __restrict__ coef, int C, int nchunk)
{
    int c = threadIdx.x;
    if (c >= C) return;
    float s = 0.f, ss = 0.f;
    for (int i = 0; i < nchunk; ++i) {
        float2 p = partial[(size_t)c * nchunk + i];
        s += p.x; ss += p.y;
    }
    const float N = 524288.f;
    float m = s / N;
    float v = ss / N - m * m;
    float rsq = rsqrtf(v + 1e-5f);
    float a = gamma[c] * rsq;
    coef[c] = make_float2(a, beta[c] - m * a);
}

// ================= finalize v2: one block per channel, [c][NCHUNK] =================
template<int NCHUNK>
__global__ __launch_bounds__(256) void bn_finalize2(const float2* __restrict__ partial,
                                                    const float* __restrict__ gamma,
                                                    const float* __restrict__ beta,
                                                    float2* __restrict__ coef)
{
    const int c = blockIdx.x, t = threadIdx.x;
    float s = 0.f, q = 0.f;
    for (int i = t; i < NCHUNK; i += 256) {
        float2 p = partial[(size_t)c * NCHUNK + i];
        s += p.x; q += p.y;
    }
    __shared__ float rs[256], rq[256];
    rs[t] = s; rq[t] = q;
    __syncthreads();
    for (int off = 128; off; off >>= 1) {
        if (t < off) { rs[t] += rs[t + off]; rq[t] += rq[t + off]; }
        __syncthreads();
    }
    if (t == 0) {
        const float N = 524288.f;
        float m = rs[0] / N;
        float v = rq[0] / N - m * m;
        float a = gamma[c] * rsqrtf(v + 1e-5f);
        coef[c] = make_float2(a, beta[c] - m * a);
    }
}

// ================= stage-4 apply: raw NHWC bf16 -> normalized NCHW f32 z =================
__global__ __launch_bounds__(256) void apply_t(const unsigned short* __restrict__ raw,
                                               const float2* __restrict__ coef,
                                               float* __restrict__ z)
{
    __shared__ float s_t[256 * 36];
    __shared__ float2 s_c[256];
    const int t = threadIdx.x;
    s_c[t] = coef[t];
    __syncthreads();

    const size_t p0 = (size_t)blockIdx.x * 32;
    const int o = t & 31, prow = t >> 5;
    #pragma unroll
    for (int it = 0; it < 4; ++it) {
        const int pxi = prow + it * 8;
        short8 v = *(const short8*)&raw[(p0 + pxi) * 256 + o * 8];
        #pragma unroll
        for (int j = 0; j < 8; ++j) {
            const int oc = o * 8 + j;
            float2 ab = s_c[oc];
            float xv = fmaf(ab.x, bf2f((unsigned short)v[j]), ab.y);
            xv = fmaxf(xv, 0.01f * xv);
            s_t[oc * 36 + (pxi ^ ((o & 7) * 4))] = xv;
        }
    }
    __syncthreads();

    const int Q = t & 7, ocr = t >> 3;
    const int b = (int)(p0 >> 16);
    const int pxl = (int)(p0 & 65535);
    #pragma unroll
    for (int pass = 0; pass < 8; ++pass) {
        const int oc = ocr + pass * 32;
        const int w = (oc >> 3) & 7;
        f32x4 vv = *(const f32x4*)&s_t[oc * 36 + ((Q ^ w) * 4)];
        *(f32x4*)&z[(((size_t)(b * 256 + oc)) << 16) + pxl + Q * 4] = vv;
    }
}

// ================= aux outputs =================
__global__ void patches_kernel(const float* __restrict__ x, const int* __restrict__ hw,
                               float* __restrict__ out)
{
    int bs = blockIdx.x;
    int b = bs >> 5;
    int h = hw[bs * 2], w = hw[bs * 2 + 1];
    int t = threadIdx.x;
    if (t < 243) {
        int c = t / 81, r = (t / 9) % 9, cc = t % 9;
        out[(size_t)bs * 243 + t] =
            x[((size_t)(b * 3 + c)) * HW + (size_t)(h - 4 + r) * IMG_W + (w - 4 + cc)];
    }
}

__global__ void gather_kernel(const float* __restrict__ z, const int* __restrict__ hw,
                              float* __restrict__ out)
{
    int bs = blockIdx.x;
    int b = bs >> 5;
    int h = hw[bs * 2], w = hw[bs * 2 + 1];
    int l = threadIdx.x;
    out[(size_t)bs * 256 + l] = z[((size_t)(b * 256 + l)) * HW + (size_t)h * IMG_W + w];
}

__global__ __launch_bounds__(256) void recon_kernel(const float* __restrict__ za,
                                                    const float* __restrict__ rw,
                                                    const float* __restrict__ rb,
                                                    float* __restrict__ out)
{
    int wave = threadIdx.x >> 6, lane = threadIdx.x & 63;
    int n0 = blockIdx.x * 16 + wave * 4;
    float acc[4][8];
    #pragma unroll
    for (int j = 0; j < 4; ++j)
        #pragma unroll
        for (int bb = 0; bb < 8; ++bb) acc[j][bb] = 0.f;

    for (int i = 0; i < 32; ++i) {
        int k = i * 256 + lane * 4;
        float4 wv[4];
        #pragma unroll
        for (int j = 0; j < 4; ++j)
            wv[j] = *(const float4*)&rw[(size_t)(n0 + j) * 8192 + k];
        #pragma unroll
        for (int bb = 0; bb < 8; ++bb) {
            float4 zv = *(const float4*)&za[(size_t)bb * 8192 + k];
            #pragma unroll
            for (int j = 0; j < 4; ++j)
                acc[j][bb] += zv.x * wv[j].x + zv.y * wv[j].y + zv.z * wv[j].z + zv.w * wv[j].w;
        }
    }
    #pragma unroll
    for (int j = 0; j < 4; ++j)
        #pragma unroll
        for (int bb = 0; bb < 8; ++bb) {
            float v = acc[j][bb];
            #pragma unroll
            for (int off = 32; off; off >>= 1) v += __shfl_down(v, off);
            if (lane == 0) out[(size_t)bb * 7776 + n0 + j] = v + rb[n0 + j];
        }
}

extern "C" void kernel_launch(void* const* d_in, const int* in_sizes, int n_in,
                              void* d_out, int out_size, void* d_ws, size_t ws_size,
                              hipStream_t stream) {
    (void)in_sizes; (void)n_in; (void)out_size; (void)ws_size;

    const float* x        = (const float*)d_in[0];
    const int* anchors    = (const int*)d_in[1];
    const int* positives  = (const int*)d_in[2];
    const float* w1 = (const float*)d_in[3];  const float* b1 = (const float*)d_in[4];
    const float* g1 = (const float*)d_in[5];  const float* be1 = (const float*)d_in[6];
    const float* w2 = (const float*)d_in[7];  const float* b2 = (const float*)d_in[8];
    const float* g2 = (const float*)d_in[9];  const float* be2 = (const float*)d_in[10];
    const float* w3 = (const float*)d_in[11]; const float* b3 = (const float*)d_in[12];
    const float* g3 = (const float*)d_in[13]; const float* be3 = (const float*)d_in[14];
    const float* w4 = (const float*)d_in[15]; const float* b4 = (const float*)d_in[16];
    const float* g4 = (const float*)d_in[17]; const float* be4 = (const float*)d_in[18];
    const float* rw = (const float*)d_in[19]; const float* rb = (const float*)d_in[20];

    float* z  = (float*)d_out;                 // [8][256][256][256] f32 normalized (final)
    float* xa = z + 134217728;
    float* xr = xa + 62208;
    float* za = xr + 62208;
    float* zp = za + 65536;

    // raw1/raw2/raw3 (NHWC bf16) overlay the z region (dead before apply_t writes z)
    char* zb = (char*)d_out;
    unsigned short* raw1 = (unsigned short*)zb;                  //  33,554,432 B
    unsigned short* raw2 = (unsigned short*)(zb + 33554432ull);  //  67,108,864 B
    unsigned short* raw3 = (unsigned short*)(zb + 100663296ull); // 134,217,728 B (ends 234.9 MB)

    char* ws = (char*)d_ws;
    unsigned short* wp   = (unsigned short*)ws;                  // <= 589,824 B
    float2* partial = (float2*)(ws + 1048576ull);                // <= 8,388,608 B
    float2* coef1   = (float2*)(ws + 10485760ull);
    float2* coef2   = coef1 + 256;
    float2* coef3   = coef2 + 256;
    float2* coef4   = coef3 + 256;
    unsigned short* raw4 = (unsigned short*)(ws + 16777216ull);  // 134,217,728 B (ends 151 MB)

    // ---- stage 1 ----
    conv1_direct<<<dim3(64, 2, 8), 256, 0, stream>>>(x, w1, b1, raw1);
    bn_stats_nhwc<32><<<256, 256, 0, stream>>>(raw1, partial);
    bn_finalize_kernel<<<1, 256, 0, stream>>>(partial, g1, be1, coef1, 32, 256);

    // ---- stage 2: block 256px x 64oc (4x1 waves, WOC=64) ----
    repack2<<<(64 * 288 + 255) / 256, 256, 0, stream>>>(w2, wp, 64, 32);
    conv_mfma3<32, 64, 4, 1, 64><<<dim3(256, 1, 8), 256, 0, stream>>>(raw1, coef1, wp, b2, raw2, partial);
    bn_finalize2<2048><<<64, 256, 0, stream>>>(partial, g2, be2, coef2);

    // ---- stage 3: block 256px x 128oc (4x1 waves, WOC=128) ----
    repack2<<<(128 * 576 + 255) / 256, 256, 0, stream>>>(w3, wp, 128, 64);
    conv_mfma3<64, 128, 4, 1, 128><<<dim3(256, 1, 8), 256, 0, stream>>>(raw2, coef2, wp, b3, raw3, partial);
    bn_finalize2<2048><<<128, 256, 0, stream>>>(partial, g3, be3, coef3);

    // ---- stage 4: block 128px x 256oc (2x2 waves, WOC=128) ----
    repack2<<<(256 * 1152 + 255) / 256, 256, 0, stream>>>(w4, wp, 256, 128);
    conv_mfma3<128, 256, 2, 2, 128><<<dim3(512, 1, 8), 256, 0, stream>>>(raw3, coef3, wp, b4, raw4, partial);
    bn_finalize2<4096><<<256, 256, 0, stream>>>(partial, g4, be4, coef4);

    // ---- stage-4 apply + NHWC->NCHW transpose into z ----
    apply_t<<<16384, 256, 0, stream>>>(raw4, coef4, z);

    // ---- aux outputs ----
    patches_kernel<<<256, 256, 0, stream>>>(x, anchors, xa);
    gather_kernel<<<256, 256, 0, stream>>>(z, anchors, za);
    gather_kernel<<<256, 256, 0, stream>>>(z, positives, zp);
    recon_kernel<<<486, 256, 0, stream>>>(za, rw, rb, xr);
}